// Round 9
// baseline (355.226 us; speedup 1.0000x reference)
//
#include <hip/hip_runtime.h>
#include <math.h>

#define BB 2
#define SS 2048
#define EE 1024
#define HH 16

typedef _Float16 f16;
typedef __attribute__((ext_vector_type(8))) _Float16 f16x8;
typedef __attribute__((ext_vector_type(4))) _Float16 f16x4;
typedef __attribute__((ext_vector_type(2))) _Float16 f16x2;
typedef __attribute__((ext_vector_type(4))) float f32x4;

union P8 { f16x8 v8; f16x2 h2[4]; };
union V8 { f16x8 v8; f16x4 v4[2]; };

// 0.125 (1/sqrt(D)) * log2(e)  -- folded into Q at the GEMM1 epilogue
#define QSCALE 0.18033688011112042f

#if __has_builtin(__builtin_amdgcn_exp2f)
#define EXP2(x) __builtin_amdgcn_exp2f(x)
#else
#define EXP2(x) exp2f(x)
#endif

static __device__ __forceinline__ f16x2 pk2(float a, float b) {
#if __has_builtin(__builtin_amdgcn_cvt_pkrtz)
  return __builtin_bit_cast(f16x2, __builtin_amdgcn_cvt_pkrtz(a, b));
#else
  f16x2 r; r[0] = (f16)a; r[1] = (f16)b; return r;
#endif
}

// async global->LDS, 16B per lane; dest = wave-uniform base + lane*16
static __device__ __forceinline__ void gl16(const void* g, void* l) {
  __builtin_amdgcn_global_load_lds(
      (const __attribute__((address_space(1))) void*)g,
      (__attribute__((address_space(3))) void*)l, 16, 0, 0);
}

// ---------------------------------------------------------------------------
// fp32 -> fp16 elementwise (n % 8 == 0)
// ---------------------------------------------------------------------------
__global__ __launch_bounds__(256) void cvt_f32_f16(
    const float* __restrict__ in, f16* __restrict__ out, int n)
{
  int i = (blockIdx.x * 256 + threadIdx.x) * 8;
  if (i >= n) return;
  float4 a = *(const float4*)(in + i);
  float4 b = *(const float4*)(in + i + 4);
  f16x8 o;
  o[0] = (f16)a.x; o[1] = (f16)a.y; o[2] = (f16)a.z; o[3] = (f16)a.w;
  o[4] = (f16)b.x; o[5] = (f16)b.y; o[6] = (f16)b.z; o[7] = (f16)b.w;
  *(f16x8*)(out + i) = o;
}

// ---------------------------------------------------------------------------
// out[n][k] = (f16) in[k][n]   (K x N fp32 -> N x K fp16), 64x64 LDS tiles
// ---------------------------------------------------------------------------
__global__ __launch_bounds__(256) void transpose_cvt(
    const float* __restrict__ in, f16* __restrict__ out, int K, int N)
{
  __shared__ float T[64][65];
  const int k0 = blockIdx.y * 64, n0 = blockIdx.x * 64;
  const int tr = threadIdx.x >> 4, tc = (threadIdx.x & 15) * 4;
#pragma unroll
  for (int i = 0; i < 4; ++i) {
    int r = tr + i * 16;
    *(float4*)&T[r][tc] = *(const float4*)(in + (size_t)(k0 + r) * N + n0 + tc);
  }
  __syncthreads();
#pragma unroll
  for (int i = 0; i < 4; ++i) {
    int nl = tr + i * 16;
    f16x4 v;
    v[0] = (f16)T[tc + 0][nl];
    v[1] = (f16)T[tc + 1][nl];
    v[2] = (f16)T[tc + 2][nl];
    v[3] = (f16)T[tc + 3][nl];
    *(f16x4*)(out + (size_t)(n0 + nl) * K + k0 + tc) = v;
  }
}

// ---------------------------------------------------------------------------
// Pack int32 bool mask -> bitmask (bit set = masked). 64 ints -> 1 u64.
// ---------------------------------------------------------------------------
__global__ __launch_bounds__(256) void pack_mask(
    const int* __restrict__ m, unsigned long long* __restrict__ bits)
{
  const int i = blockIdx.x * 256 + threadIdx.x;
  const unsigned long long bal = __ballot(m[i] != 0);
  if ((threadIdx.x & 63) == 0) bits[i >> 6] = bal;
}

// ---------------------------------------------------------------------------
// MFMA fp16 GEMM, m97 structure: 128x128 tile, BK=32, global_load_lds w16
// staging into linear LDS with both-sides XOR chunk swizzle.
// mode 0: qkv epilogue (Q cols pre-scaled by QSCALE; K raw; V -> vT).
// mode 1: fp32 out + bias.
// ---------------------------------------------------------------------------
__global__ __launch_bounds__(256) void gemm_f16(
    const f16* __restrict__ A, const f16* __restrict__ Bt,
    const float* __restrict__ bias, int M, int N, int K, int mode,
    f16* __restrict__ oQK, f16* __restrict__ oVT, float* __restrict__ oF32)
{
  __shared__ f16 Ah[128 * 32];
  __shared__ f16 Bh[128 * 32];

  const int t = threadIdx.x;
  const int l = t & 63, w = t >> 6;
  const int l15 = l & 15, l4 = l >> 4;
  const int wr = w >> 1, wc = w & 1;
  const int n0 = blockIdx.x * 128, m0 = blockIdx.y * 128;

  const int srow = l >> 2;
  const int gch  = (l & 3) ^ (srow & 3);
  const f16* Ap0 = A + (size_t)(m0 + w * 32 + srow) * K + gch * 8;
  const f16* Ap1 = Ap0 + (size_t)16 * K;
  const f16* Bp0 = Bt + (size_t)(n0 + w * 32 + srow) * K + gch * 8;
  const f16* Bp1 = Bp0 + (size_t)16 * K;
  f16* ldsA0 = &Ah[(w * 32) * 32];
  f16* ldsA1 = &Ah[(w * 32 + 16) * 32];
  f16* ldsB0 = &Bh[(w * 32) * 32];
  f16* ldsB1 = &Bh[(w * 32 + 16) * 32];

  f32x4 acc[4][4] = {};
  const int csw = (l15 & 3);

  for (int k0 = 0; k0 < K; k0 += 32) {
    gl16(Ap0 + k0, ldsA0);
    gl16(Ap1 + k0, ldsA1);
    gl16(Bp0 + k0, ldsB0);
    gl16(Bp1 + k0, ldsB1);
    __syncthreads();

    f16x8 af[4], bf[4];
#pragma unroll
    for (int mr = 0; mr < 4; ++mr) {
      const int row = wr * 64 + mr * 16 + l15;
      af[mr] = *(const f16x8*)&Ah[row * 32 + ((l4 ^ csw) * 8)];
    }
#pragma unroll
    for (int nr = 0; nr < 4; ++nr) {
      const int row = wc * 64 + nr * 16 + l15;
      bf[nr] = *(const f16x8*)&Bh[row * 32 + ((l4 ^ csw) * 8)];
    }
    __builtin_amdgcn_s_setprio(1);
#pragma unroll
    for (int mr = 0; mr < 4; ++mr)
#pragma unroll
      for (int nr = 0; nr < 4; ++nr)
        acc[mr][nr] = __builtin_amdgcn_mfma_f32_16x16x32_f16(
            af[mr], bf[nr], acc[mr][nr], 0, 0, 0);
    __builtin_amdgcn_s_setprio(0);
    __syncthreads();
  }

  if (mode == 1) {
#pragma unroll
    for (int nr = 0; nr < 4; ++nr) {
      const int n = n0 + wc * 64 + nr * 16 + l15;
      const float bv = bias[n];
#pragma unroll
      for (int mr = 0; mr < 4; ++mr)
#pragma unroll
        for (int j = 0; j < 4; ++j) {
          const int m = m0 + wr * 64 + mr * 16 + l4 * 4 + j;
          oF32[(size_t)m * N + n] = acc[mr][nr][j] + bv;
        }
    }
  } else {
#pragma unroll
    for (int nr = 0; nr < 4; ++nr) {
      const int n = n0 + wc * 64 + nr * 16 + l15;
      const float bv = bias[n];
      if (n < 2048) {
        const float qs = (n < 1024) ? QSCALE : 1.0f;
#pragma unroll
        for (int mr = 0; mr < 4; ++mr)
#pragma unroll
          for (int j = 0; j < 4; ++j) {
            const int m = m0 + wr * 64 + mr * 16 + l4 * 4 + j;
            oQK[(size_t)m * 2048 + n] = (f16)((acc[mr][nr][j] + bv) * qs);
          }
      } else {
        const int hh = (n - 2048) >> 6;
        const int d = (n - 2048) & 63;
#pragma unroll
        for (int mr = 0; mr < 4; ++mr) {
          const int tok0 = m0 + wr * 64 + mr * 16 + l4 * 4;
          const int bq = tok0 >> 11, sq = tok0 & 2047;
          f16x4 v;
          v[0] = (f16)(acc[mr][nr][0] + bv);
          v[1] = (f16)(acc[mr][nr][1] + bv);
          v[2] = (f16)(acc[mr][nr][2] + bv);
          v[3] = (f16)(acc[mr][nr][3] + bv);
          *(f16x4*)(oVT + ((size_t)(bq * 16 + hh) * 64 + d) * SS + sq) = v;
        }
      }
    }
  }
}

// ---------------------------------------------------------------------------
// MFMA attention v5, key-split 2-way. Grid (16, 32, 2); 4 waves x 32 q-rows.
// K double-buffered in 16KB LDS (XOR-swizzled, reg-staged); V read DIRECT
// global->reg per lane (issued at BODY top, consumed in PV ~400cyc later;
// vT is L2-resident). 16KB LDS/block -> 4 blocks/CU residency.
// No-max softmax => additive partials; combine kernel merges.
// ---------------------------------------------------------------------------
__global__ __launch_bounds__(256, 4) void attn_mfma(
    const f16* __restrict__ qkbuf, const f16* __restrict__ vT,
    const unsigned long long* __restrict__ mbits,
    f16* __restrict__ Opart, float* __restrict__ Lpart)
{
  __shared__ f16 Kds[2][64 * 64];   // [key][d], chunk-swizzled; 16 KB total

  const int t = threadIdx.x;
  const int w = t >> 6, l = t & 63, l15 = l & 15, l4 = l >> 4;
  const int bh = blockIdx.y, b = bh >> 4, h = bh & 15;
  const int ks = blockIdx.z;
  const int qbase = blockIdx.x * 128 + w * 32;

  f16x8 q00, q01, q10, q11;
  {
    const size_t r0 = (size_t)(b * SS + qbase + l15) * 2048 + h * 64;
    const size_t r1 = (size_t)(b * SS + qbase + 16 + l15) * 2048 + h * 64;
    q00 = *(const f16x8*)(qkbuf + r0 + l4 * 8);
    q01 = *(const f16x8*)(qkbuf + r0 + 32 + l4 * 8);
    q10 = *(const f16x8*)(qkbuf + r1 + l4 * 8);
    q11 = *(const f16x8*)(qkbuf + r1 + 32 + l4 * 8);
  }

  f32x4 accA[4] = {}, accB[4] = {};
  f32x4 accLA = {}, accLB = {};
  f16x8 ones;
#pragma unroll
  for (int i = 0; i < 8; ++i) ones[i] = (f16)1.0f;

  const unsigned long long* mA =
      mbits + (size_t)(b * SS + qbase + l15) * 32 + ks * 16;
  const unsigned long long* mB =
      mbits + (size_t)(b * SS + qbase + 16 + l15) * 32 + ks * 16;

  // K staging (reg -> swizzled LDS): thread t covers rows {srow, srow+32}
  const int srow = t >> 3;              // 0..31
  const int scb  = (t & 7) * 8;
  const int sws  = (srow & 7) << 3;
  const f16* kb = qkbuf + (size_t)b * SS * 2048 + 1024 + h * 64 + scb +
                  (size_t)ks * 1024 * 2048;
  // V direct-load base: row d = dg*16 + l15, key chunk at l4*4
  const f16* vbase = vT + ((size_t)bh * 64 + l15) * SS + ks * 1024 + l4 * 4;

  f16x8 kr0, kr1;
#define LOADT(kt)                                                         \
  {                                                                       \
    kr0 = *(const f16x8*)(kb + (size_t)((kt) + srow) * 2048);             \
    kr1 = *(const f16x8*)(kb + (size_t)((kt) + srow + 32) * 2048);        \
  }
#define COMMIT(bi)                                                        \
  {                                                                       \
    *(f16x8*)&Kds[bi][srow * 64 + (scb ^ sws)]        = kr0;              \
    *(f16x8*)&Kds[bi][(srow + 32) * 64 + (scb ^ sws)] = kr1;              \
  }

  LOADT(0)
  COMMIT(0)
  LOADT(64)
  __syncthreads();

  const int swr = (l15 & 7) << 3;

#define BODY(cur, tI)                                                         \
  {                                                                           \
    /* V for this tile: 16 x 8B direct loads, consumed in PV below */         \
    f16x4 vr[4][2][2];                                                        \
    _Pragma("unroll")                                                         \
    for (int dg = 0; dg < 4; ++dg)                                            \
      _Pragma("unroll")                                                       \
      for (int sg = 0; sg < 2; ++sg) {                                        \
        vr[dg][sg][0] = *(const f16x4*)(vbase + (size_t)(dg * 16) * SS +      \
                                        (tI) * 64 + sg * 32);                 \
        vr[dg][sg][1] = *(const f16x4*)(vbase + (size_t)(dg * 16) * SS +      \
                                        (tI) * 64 + sg * 32 + 16);            \
      }                                                                       \
    const unsigned long long mbA = mA[tI];                                    \
    const unsigned long long mbB = mB[tI];                                    \
    _Pragma("unroll")                                                         \
    for (int sg = 0; sg < 2; ++sg) {                                          \
      float pA[8], pB[8];                                                     \
      _Pragma("unroll")                                                       \
      for (int gh = 0; gh < 2; ++gh) {                                        \
        const int g = sg * 2 + gh;                                            \
        const f16* krow = &Kds[cur][(g * 16 + l15) * 64];                     \
        const f16x8 k0 = *(const f16x8*)(krow + ((l4 * 8) ^ swr));            \
        const f16x8 k1 = *(const f16x8*)(krow + ((32 + l4 * 8) ^ swr));       \
        __builtin_amdgcn_s_setprio(1);                                        \
        f32x4 SA = __builtin_amdgcn_mfma_f32_16x16x32_f16(                    \
            k0, q00, (f32x4){0.f, 0.f, 0.f, 0.f}, 0, 0, 0);                   \
        SA = __builtin_amdgcn_mfma_f32_16x16x32_f16(k1, q01, SA, 0, 0, 0);    \
        f32x4 SB = __builtin_amdgcn_mfma_f32_16x16x32_f16(                    \
            k0, q10, (f32x4){0.f, 0.f, 0.f, 0.f}, 0, 0, 0);                   \
        SB = __builtin_amdgcn_mfma_f32_16x16x32_f16(k1, q11, SB, 0, 0, 0);    \
        __builtin_amdgcn_s_setprio(0);                                        \
        const unsigned int nibA = (unsigned int)(mbA >> (g * 16 + l4 * 4));   \
        const unsigned int nibB = (unsigned int)(mbB >> (g * 16 + l4 * 4));   \
        _Pragma("unroll")                                                     \
        for (int j = 0; j < 4; ++j) {                                         \
          pA[gh * 4 + j] = ((nibA >> j) & 1u) ? 1.0f : EXP2(SA[j]);           \
          pB[gh * 4 + j] = ((nibB >> j) & 1u) ? 1.0f : EXP2(SB[j]);           \
        }                                                                     \
      }                                                                       \
      P8 uA, uB;                                                              \
      uA.h2[0] = pk2(pA[0], pA[1]); uA.h2[1] = pk2(pA[2], pA[3]);             \
      uA.h2[2] = pk2(pA[4], pA[5]); uA.h2[3] = pk2(pA[6], pA[7]);             \
      uB.h2[0] = pk2(pB[0], pB[1]); uB.h2[1] = pk2(pB[2], pB[3]);             \
      uB.h2[2] = pk2(pB[4], pB[5]); uB.h2[3] = pk2(pB[6], pB[7]);             \
      __builtin_amdgcn_s_setprio(1);                                          \
      _Pragma("unroll")                                                       \
      for (int dg = 0; dg < 4; ++dg) {                                        \
        V8 uv;                                                                \
        uv.v4[0] = vr[dg][sg][0];                                             \
        uv.v4[1] = vr[dg][sg][1];                                             \
        accA[dg] = __builtin_amdgcn_mfma_f32_16x16x32_f16(uA.v8, uv.v8,       \
                                                          accA[dg], 0, 0, 0); \
        accB[dg] = __builtin_amdgcn_mfma_f32_16x16x32_f16(uB.v8, uv.v8,       \
                                                          accB[dg], 0, 0, 0); \
      }                                                                       \
      accLA = __builtin_amdgcn_mfma_f32_16x16x32_f16(uA.v8, ones, accLA,      \
                                                     0, 0, 0);                \
      accLB = __builtin_amdgcn_mfma_f32_16x16x32_f16(uB.v8, ones, accLB,      \
                                                     0, 0, 0);                \
      __builtin_amdgcn_s_setprio(0);                                          \
    }                                                                         \
    if ((tI) + 1 < 16) {                                                      \
      COMMIT((cur) ^ 1)                                                       \
      if ((tI) + 2 < 16) LOADT(((tI) + 2) * 64)                               \
    }                                                                         \
    __syncthreads();                                                          \
  }

  for (int tI = 0; tI < 16; tI += 2) {
    BODY(0, tI)
    BODY(1, tI + 1)
  }

  // Partial outputs: raw PV sums (f16) + denominators (f32, via ones-MFMA,
  // identical across l15 -> lane l15==0 writes).
  const size_t obase = (size_t)ks * 4096 * EE;
#pragma unroll
  for (int j = 0; j < 4; ++j) {
    const int qr = l4 * 4 + j;
    const size_t rowA = (size_t)(b * SS + qbase + qr) * EE + h * 64 + l15;
    const size_t rowB = (size_t)(b * SS + qbase + 16 + qr) * EE + h * 64 + l15;
#pragma unroll
    for (int dg = 0; dg < 4; ++dg) {
      Opart[obase + rowA + dg * 16] = (f16)accA[dg][j];
      Opart[obase + rowB + dg * 16] = (f16)accB[dg][j];
    }
    if (l15 == 0) {
      Lpart[(size_t)ks * 4096 * HH + (size_t)(b * SS + qbase + qr) * HH + h] =
          accLA[j];
      Lpart[(size_t)ks * 4096 * HH +
            (size_t)(b * SS + qbase + 16 + qr) * HH + h] = accLB[j];
    }
  }
}

// ---------------------------------------------------------------------------
// combine: aout = (O0 + O1) / (L0 + L1), f16 out. 8 elems/thread.
// ---------------------------------------------------------------------------
__global__ __launch_bounds__(256) void combine(
    const f16* __restrict__ Opart, const float* __restrict__ Lpart,
    f16* __restrict__ aout)
{
  const size_t i = ((size_t)blockIdx.x * 256 + threadIdx.x) * 8;
  const int token = (int)(i >> 10);
  const int h = (int)((i >> 6) & 15);
  const float inv =
      1.0f / (Lpart[(size_t)token * HH + h] +
              Lpart[(size_t)4096 * HH + (size_t)token * HH + h]);
  const f16x8 o0 = *(const f16x8*)(Opart + i);
  const f16x8 o1 = *(const f16x8*)(Opart + (size_t)4096 * EE + i);
  f16x8 o;
#pragma unroll
  for (int j = 0; j < 8; ++j)
    o[j] = (f16)(((float)o0[j] + (float)o1[j]) * inv);
  *(f16x8*)(aout + i) = o;
}

// ---------------------------------------------------------------------------
// Workspace layout (45.6 MB, live-range based; no overlap between live bufs):
//   [ 0.0 ..  2.1)  fckT   (transpose2 .. gemm2)
//   [ 2.1 .. 18.9)  qk     (gemm1 .. attn)   -- reused as aoutH after attn
//   [18.9 .. 27.3)  vT     (gemm1 .. attn)
//   [27.3 .. 28.3)  mbits  (pack .. attn)
//   [28.3 .. 28.8)  Lp     (attn .. combine)
//   [28.8 .. 45.6)  scratch: xh(8.4)+Wt(6.3) (prep .. gemm1), then
//                   Opart 16.8 contiguous    (attn .. combine)
// ---------------------------------------------------------------------------
extern "C" void kernel_launch(void* const* d_in, const int* in_sizes, int n_in,
                              void* d_out, int out_size, void* d_ws,
                              size_t ws_size, hipStream_t stream)
{
  (void)in_sizes; (void)n_in; (void)out_size; (void)ws_size;
  const float* x   = (const float*)d_in[0];
  const int* mask  = (const int*)d_in[1];   // jnp bool staged as int32
  const float* wk  = (const float*)d_in[2];
  const float* wb  = (const float*)d_in[3];
  const float* fck = (const float*)d_in[4];
  const float* fcb = (const float*)d_in[5];
  float* out       = (float*)d_out;

  char* ws = (char*)d_ws;
  f16* fckT = (f16*)(ws);                                   //  2,097,152 B
  f16* qk   = (f16*)(ws + 2097152);                         // 16,777,216 B
  f16* vT   = (f16*)(ws + 18874368);                        //  8,388,608 B
  unsigned long long* mbits = (unsigned long long*)(ws + 27262976); // 1 MB
  float* Lp = (float*)(ws + 28311552);                      //    524,288 B
  char* scratch = ws + 28835840;
  f16* xh    = (f16*)scratch;                               //  8,388,608 B
  f16* Wt    = (f16*)(scratch + 8388608);                   //  6,291,456 B
  f16* Opart = (f16*)scratch;                               // 16,777,216 B
  f16* aoutH = qk;                                          // reuse (qk dead)

  // prep
  cvt_f32_f16<<<4096 * 1024 / (8 * 256), 256, 0, stream>>>(x, xh, 4096 * 1024);
  transpose_cvt<<<dim3(3072 / 64, 1024 / 64), 256, 0, stream>>>(wk, Wt, 1024, 3072);
  transpose_cvt<<<dim3(1024 / 64, 1024 / 64), 256, 0, stream>>>(fck, fckT, 1024, 1024);
  pack_mask<<<BB * SS * SS / 256, 256, 0, stream>>>(mask, mbits);

  // qkv = x @ w_kernel + w_bias  (MFMA fp16) -> qk f16 (Q pre-scaled) + vT f16
  gemm_f16<<<dim3(3072 / 128, 4096 / 128), 256, 0, stream>>>(
      xh, Wt, wb, 4096, 3072, 1024, 0, qk, vT, nullptr);

  // key-split attention -> partials (Opart overwrites dead xh/Wt scratch)
  attn_mfma<<<dim3(SS / 128, BB * HH, 2), 256, 0, stream>>>(
      qk, vT, mbits, Opart, Lp);
  combine<<<4096 * 1024 / (8 * 256), 256, 0, stream>>>(Opart, Lp, aoutH);

  // out = aout @ fc_kernel + fc_bias  (MFMA fp16, fp32 out)
  gemm_f16<<<dim3(1024 / 128, 4096 / 128), 256, 0, stream>>>(
      aoutH, fckT, fcb, 4096, 1024, 1024, 1, nullptr, nullptr, out);
}

// Round 10
// 243.260 us; speedup vs baseline: 1.4603x; 1.4603x over previous
//
#include <hip/hip_runtime.h>
#include <math.h>

#define BB 2
#define SS 2048
#define EE 1024
#define HH 16

typedef _Float16 f16;
typedef __attribute__((ext_vector_type(8))) _Float16 f16x8;
typedef __attribute__((ext_vector_type(4))) _Float16 f16x4;
typedef __attribute__((ext_vector_type(2))) _Float16 f16x2;
typedef __attribute__((ext_vector_type(4))) float f32x4;

union P8 { f16x8 v8; f16x2 h2[4]; };
union V8 { f16x8 v8; f16x4 v4[2]; };

// 0.125 (1/sqrt(D)) * log2(e)  -- folded into Q at the GEMM1 epilogue
#define QSCALE 0.18033688011112042f

#if __has_builtin(__builtin_amdgcn_exp2f)
#define EXP2(x) __builtin_amdgcn_exp2f(x)
#else
#define EXP2(x) exp2f(x)
#endif

static __device__ __forceinline__ f16x2 pk2(float a, float b) {
#if __has_builtin(__builtin_amdgcn_cvt_pkrtz)
  return __builtin_bit_cast(f16x2, __builtin_amdgcn_cvt_pkrtz(a, b));
#else
  f16x2 r; r[0] = (f16)a; r[1] = (f16)b; return r;
#endif
}

// async global->LDS, 16B per lane; dest = wave-uniform base + lane*16
static __device__ __forceinline__ void gl16(const void* g, void* l) {
  __builtin_amdgcn_global_load_lds(
      (const __attribute__((address_space(1))) void*)g,
      (__attribute__((address_space(3))) void*)l, 16, 0, 0);
}

// ---------------------------------------------------------------------------
// fp32 -> fp16 elementwise (n % 8 == 0)
// ---------------------------------------------------------------------------
__global__ __launch_bounds__(256) void cvt_f32_f16(
    const float* __restrict__ in, f16* __restrict__ out, int n)
{
  int i = (blockIdx.x * 256 + threadIdx.x) * 8;
  if (i >= n) return;
  float4 a = *(const float4*)(in + i);
  float4 b = *(const float4*)(in + i + 4);
  f16x8 o;
  o[0] = (f16)a.x; o[1] = (f16)a.y; o[2] = (f16)a.z; o[3] = (f16)a.w;
  o[4] = (f16)b.x; o[5] = (f16)b.y; o[6] = (f16)b.z; o[7] = (f16)b.w;
  *(f16x8*)(out + i) = o;
}

// ---------------------------------------------------------------------------
// out[n][k] = (f16) in[k][n]   (K x N fp32 -> N x K fp16), 64x64 LDS tiles
// ---------------------------------------------------------------------------
__global__ __launch_bounds__(256) void transpose_cvt(
    const float* __restrict__ in, f16* __restrict__ out, int K, int N)
{
  __shared__ float T[64][65];
  const int k0 = blockIdx.y * 64, n0 = blockIdx.x * 64;
  const int tr = threadIdx.x >> 4, tc = (threadIdx.x & 15) * 4;
#pragma unroll
  for (int i = 0; i < 4; ++i) {
    int r = tr + i * 16;
    *(float4*)&T[r][tc] = *(const float4*)(in + (size_t)(k0 + r) * N + n0 + tc);
  }
  __syncthreads();
#pragma unroll
  for (int i = 0; i < 4; ++i) {
    int nl = tr + i * 16;
    f16x4 v;
    v[0] = (f16)T[tc + 0][nl];
    v[1] = (f16)T[tc + 1][nl];
    v[2] = (f16)T[tc + 2][nl];
    v[3] = (f16)T[tc + 3][nl];
    *(f16x4*)(out + (size_t)(n0 + nl) * K + k0 + tc) = v;
  }
}

// ---------------------------------------------------------------------------
// Pack int32 bool mask -> bitmask (bit set = masked). 64 ints -> 1 u64.
// ---------------------------------------------------------------------------
__global__ __launch_bounds__(256) void pack_mask(
    const int* __restrict__ m, unsigned long long* __restrict__ bits)
{
  const int i = blockIdx.x * 256 + threadIdx.x;
  const unsigned long long bal = __ballot(m[i] != 0);
  if ((threadIdx.x & 63) == 0) bits[i >> 6] = bal;
}

// ---------------------------------------------------------------------------
// MFMA fp16 GEMM, m97 structure: 128x128 tile, BK=32, global_load_lds w16
// staging into linear LDS with both-sides XOR chunk swizzle.
// mode 0: qkv epilogue (Q cols pre-scaled by QSCALE; K raw; V -> vT).
// mode 1: fp32 out + bias.
// ---------------------------------------------------------------------------
__global__ __launch_bounds__(256) void gemm_f16(
    const f16* __restrict__ A, const f16* __restrict__ Bt,
    const float* __restrict__ bias, int M, int N, int K, int mode,
    f16* __restrict__ oQK, f16* __restrict__ oVT, float* __restrict__ oF32)
{
  __shared__ f16 Ah[128 * 32];
  __shared__ f16 Bh[128 * 32];

  const int t = threadIdx.x;
  const int l = t & 63, w = t >> 6;
  const int l15 = l & 15, l4 = l >> 4;
  const int wr = w >> 1, wc = w & 1;
  const int n0 = blockIdx.x * 128, m0 = blockIdx.y * 128;

  const int srow = l >> 2;
  const int gch  = (l & 3) ^ (srow & 3);
  const f16* Ap0 = A + (size_t)(m0 + w * 32 + srow) * K + gch * 8;
  const f16* Ap1 = Ap0 + (size_t)16 * K;
  const f16* Bp0 = Bt + (size_t)(n0 + w * 32 + srow) * K + gch * 8;
  const f16* Bp1 = Bp0 + (size_t)16 * K;
  f16* ldsA0 = &Ah[(w * 32) * 32];
  f16* ldsA1 = &Ah[(w * 32 + 16) * 32];
  f16* ldsB0 = &Bh[(w * 32) * 32];
  f16* ldsB1 = &Bh[(w * 32 + 16) * 32];

  f32x4 acc[4][4] = {};
  const int csw = (l15 & 3);

  for (int k0 = 0; k0 < K; k0 += 32) {
    gl16(Ap0 + k0, ldsA0);
    gl16(Ap1 + k0, ldsA1);
    gl16(Bp0 + k0, ldsB0);
    gl16(Bp1 + k0, ldsB1);
    __syncthreads();

    f16x8 af[4], bf[4];
#pragma unroll
    for (int mr = 0; mr < 4; ++mr) {
      const int row = wr * 64 + mr * 16 + l15;
      af[mr] = *(const f16x8*)&Ah[row * 32 + ((l4 ^ csw) * 8)];
    }
#pragma unroll
    for (int nr = 0; nr < 4; ++nr) {
      const int row = wc * 64 + nr * 16 + l15;
      bf[nr] = *(const f16x8*)&Bh[row * 32 + ((l4 ^ csw) * 8)];
    }
    __builtin_amdgcn_s_setprio(1);
#pragma unroll
    for (int mr = 0; mr < 4; ++mr)
#pragma unroll
      for (int nr = 0; nr < 4; ++nr)
        acc[mr][nr] = __builtin_amdgcn_mfma_f32_16x16x32_f16(
            af[mr], bf[nr], acc[mr][nr], 0, 0, 0);
    __builtin_amdgcn_s_setprio(0);
    __syncthreads();
  }

  if (mode == 1) {
#pragma unroll
    for (int nr = 0; nr < 4; ++nr) {
      const int n = n0 + wc * 64 + nr * 16 + l15;
      const float bv = bias[n];
#pragma unroll
      for (int mr = 0; mr < 4; ++mr)
#pragma unroll
        for (int j = 0; j < 4; ++j) {
          const int m = m0 + wr * 64 + mr * 16 + l4 * 4 + j;
          oF32[(size_t)m * N + n] = acc[mr][nr][j] + bv;
        }
    }
  } else {
#pragma unroll
    for (int nr = 0; nr < 4; ++nr) {
      const int n = n0 + wc * 64 + nr * 16 + l15;
      const float bv = bias[n];
      if (n < 2048) {
        const float qs = (n < 1024) ? QSCALE : 1.0f;
#pragma unroll
        for (int mr = 0; mr < 4; ++mr)
#pragma unroll
          for (int j = 0; j < 4; ++j) {
            const int m = m0 + wr * 64 + mr * 16 + l4 * 4 + j;
            oQK[(size_t)m * 2048 + n] = (f16)((acc[mr][nr][j] + bv) * qs);
          }
      } else {
        const int hh = (n - 2048) >> 6;
        const int d = (n - 2048) & 63;
#pragma unroll
        for (int mr = 0; mr < 4; ++mr) {
          const int tok0 = m0 + wr * 64 + mr * 16 + l4 * 4;
          const int bq = tok0 >> 11, sq = tok0 & 2047;
          f16x4 v;
          v[0] = (f16)(acc[mr][nr][0] + bv);
          v[1] = (f16)(acc[mr][nr][1] + bv);
          v[2] = (f16)(acc[mr][nr][2] + bv);
          v[3] = (f16)(acc[mr][nr][3] + bv);
          *(f16x4*)(oVT + ((size_t)(bq * 16 + hh) * 64 + d) * SS + sq) = v;
        }
      }
    }
  }
}

// ---------------------------------------------------------------------------
// MFMA attention v6, key-split 2-way. Grid (16, 32, 2); 4 waves x 32 q-rows.
// KVBLK=32, double-buffered ~17KB LDS: K XOR-swizzled [2][32*64],
// V padded [2][64][36] (reg-staged coalesced, b64 writes -> padding legal).
// 1 barrier/tile; setprio around MFMA clusters; unrolled x2.
// No-max softmax => additive partials; combine merges.
// ---------------------------------------------------------------------------
#define VPAD 36
__global__ __launch_bounds__(256, 4) void attn_mfma(
    const f16* __restrict__ qkbuf, const f16* __restrict__ vT,
    const unsigned long long* __restrict__ mbits,
    f16* __restrict__ Opart, float* __restrict__ Lpart)
{
  __shared__ f16 Kds[2][32 * 64];     // [key][d], chunk-swizzled, 8 KB
  __shared__ f16 Vds[2][64 * VPAD];   // [d][key+pad], 9 KB

  const int t = threadIdx.x;
  const int w = t >> 6, l = t & 63, l15 = l & 15, l4 = l >> 4;
  const int bh = blockIdx.y, b = bh >> 4, h = bh & 15;
  const int ks = blockIdx.z;
  const int qbase = blockIdx.x * 128 + w * 32;

  f16x8 q00, q01, q10, q11;
  {
    const size_t r0 = (size_t)(b * SS + qbase + l15) * 2048 + h * 64;
    const size_t r1 = (size_t)(b * SS + qbase + 16 + l15) * 2048 + h * 64;
    q00 = *(const f16x8*)(qkbuf + r0 + l4 * 8);
    q01 = *(const f16x8*)(qkbuf + r0 + 32 + l4 * 8);
    q10 = *(const f16x8*)(qkbuf + r1 + l4 * 8);
    q11 = *(const f16x8*)(qkbuf + r1 + 32 + l4 * 8);
  }

  f32x4 accA[4] = {}, accB[4] = {};
  f32x4 accLA = {}, accLB = {};
  f16x8 ones;
#pragma unroll
  for (int i = 0; i < 8; ++i) ones[i] = (f16)1.0f;

  // mask rows as u32 per 32-key tile
  const unsigned int* mA =
      (const unsigned int*)mbits + (size_t)(b * SS + qbase + l15) * 64 + ks * 32;
  const unsigned int* mB =
      (const unsigned int*)mbits + (size_t)(b * SS + qbase + 16 + l15) * 64 + ks * 32;

  // K staging: thread t covers row srow (0..31), 16B chunk scb
  const int srow = t >> 3;
  const int scb  = (t & 7) * 8;
  const int sws  = (srow & 7) << 3;
  const f16* kb = qkbuf + (size_t)b * SS * 2048 + 1024 + h * 64 + scb +
                  (size_t)ks * 1024 * 2048;
  // V staging: thread t covers d-row vd (0..63), 8-key chunk vkb
  const int vd  = t >> 2;
  const int vkb = (t & 3) * 8;
  const f16* vb = vT + ((size_t)bh * 64 + vd) * SS + ks * 1024 + vkb;

  f16x8 kr0; V8 vr0;
#define LOADT(kt)                                                         \
  {                                                                       \
    kr0 = *(const f16x8*)(kb + (size_t)((kt) + srow) * 2048);             \
    vr0.v8 = *(const f16x8*)(vb + (kt));                                  \
  }
#define COMMIT(bi)                                                        \
  {                                                                       \
    *(f16x8*)&Kds[bi][srow * 64 + (scb ^ sws)] = kr0;                     \
    *(f16x4*)&Vds[bi][vd * VPAD + vkb]     = vr0.v4[0];                   \
    *(f16x4*)&Vds[bi][vd * VPAD + vkb + 4] = vr0.v4[1];                   \
  }

  LOADT(0)
  COMMIT(0)
  LOADT(32)
  __syncthreads();

  const int swr = (l15 & 7) << 3;

#define BODY(cur, tI)                                                         \
  {                                                                           \
    const unsigned int mbA = mA[tI];                                          \
    const unsigned int mbB = mB[tI];                                          \
    float pA[8], pB[8];                                                       \
    _Pragma("unroll")                                                         \
    for (int g = 0; g < 2; ++g) {                                             \
      const f16* krow = &Kds[cur][(g * 16 + l15) * 64];                       \
      const f16x8 k0 = *(const f16x8*)(krow + ((l4 * 8) ^ swr));              \
      const f16x8 k1 = *(const f16x8*)(krow + ((32 + l4 * 8) ^ swr));         \
      __builtin_amdgcn_s_setprio(1);                                          \
      f32x4 SA = __builtin_amdgcn_mfma_f32_16x16x32_f16(                      \
          k0, q00, (f32x4){0.f, 0.f, 0.f, 0.f}, 0, 0, 0);                     \
      SA = __builtin_amdgcn_mfma_f32_16x16x32_f16(k1, q01, SA, 0, 0, 0);      \
      f32x4 SB = __builtin_amdgcn_mfma_f32_16x16x32_f16(                      \
          k0, q10, (f32x4){0.f, 0.f, 0.f, 0.f}, 0, 0, 0);                     \
      SB = __builtin_amdgcn_mfma_f32_16x16x32_f16(k1, q11, SB, 0, 0, 0);      \
      __builtin_amdgcn_s_setprio(0);                                          \
      const unsigned int nibA = mbA >> (g * 16 + l4 * 4);                     \
      const unsigned int nibB = mbB >> (g * 16 + l4 * 4);                     \
      _Pragma("unroll")                                                       \
      for (int j = 0; j < 4; ++j) {                                           \
        pA[g * 4 + j] = ((nibA >> j) & 1u) ? 1.0f : EXP2(SA[j]);              \
        pB[g * 4 + j] = ((nibB >> j) & 1u) ? 1.0f : EXP2(SB[j]);              \
      }                                                                       \
    }                                                                         \
    P8 uA, uB;                                                                \
    uA.h2[0] = pk2(pA[0], pA[1]); uA.h2[1] = pk2(pA[2], pA[3]);               \
    uA.h2[2] = pk2(pA[4], pA[5]); uA.h2[3] = pk2(pA[6], pA[7]);               \
    uB.h2[0] = pk2(pB[0], pB[1]); uB.h2[1] = pk2(pB[2], pB[3]);               \
    uB.h2[2] = pk2(pB[4], pB[5]); uB.h2[3] = pk2(pB[6], pB[7]);               \
    __builtin_amdgcn_s_setprio(1);                                            \
    _Pragma("unroll")                                                         \
    for (int dg = 0; dg < 4; ++dg) {                                          \
      const f16* vrow = &Vds[cur][(dg * 16 + l15) * VPAD];                    \
      V8 uv;                                                                  \
      uv.v4[0] = *(const f16x4*)(vrow + l4 * 4);                              \
      uv.v4[1] = *(const f16x4*)(vrow + 16 + l4 * 4);                         \
      accA[dg] = __builtin_amdgcn_mfma_f32_16x16x32_f16(uA.v8, uv.v8,         \
                                                        accA[dg], 0, 0, 0);   \
      accB[dg] = __builtin_amdgcn_mfma_f32_16x16x32_f16(uB.v8, uv.v8,         \
                                                        accB[dg], 0, 0, 0);   \
    }                                                                         \
    accLA = __builtin_amdgcn_mfma_f32_16x16x32_f16(uA.v8, ones, accLA,        \
                                                   0, 0, 0);                  \
    accLB = __builtin_amdgcn_mfma_f32_16x16x32_f16(uB.v8, ones, accLB,        \
                                                   0, 0, 0);                  \
    __builtin_amdgcn_s_setprio(0);                                            \
    if ((tI) + 1 < 32) {                                                      \
      COMMIT((cur) ^ 1)                                                       \
      if ((tI) + 2 < 32) LOADT(((tI) + 2) * 32)                               \
    }                                                                         \
    __syncthreads();                                                          \
  }

  for (int tI = 0; tI < 32; tI += 2) {
    BODY(0, tI)
    BODY(1, tI + 1)
  }

  // Partial outputs: raw PV sums (f16) + denominators (f32).
  const size_t obase = (size_t)ks * 4096 * EE;
#pragma unroll
  for (int j = 0; j < 4; ++j) {
    const int qr = l4 * 4 + j;
    const size_t rowA = (size_t)(b * SS + qbase + qr) * EE + h * 64 + l15;
    const size_t rowB = (size_t)(b * SS + qbase + 16 + qr) * EE + h * 64 + l15;
#pragma unroll
    for (int dg = 0; dg < 4; ++dg) {
      Opart[obase + rowA + dg * 16] = (f16)accA[dg][j];
      Opart[obase + rowB + dg * 16] = (f16)accB[dg][j];
    }
    if (l15 == 0) {
      Lpart[(size_t)ks * 4096 * HH + (size_t)(b * SS + qbase + qr) * HH + h] =
          accLA[j];
      Lpart[(size_t)ks * 4096 * HH +
            (size_t)(b * SS + qbase + 16 + qr) * HH + h] = accLB[j];
    }
  }
}

// ---------------------------------------------------------------------------
// combine: aout = (O0 + O1) / (L0 + L1), f16 out. 8 elems/thread.
// ---------------------------------------------------------------------------
__global__ __launch_bounds__(256) void combine(
    const f16* __restrict__ Opart, const float* __restrict__ Lpart,
    f16* __restrict__ aout)
{
  const size_t i = ((size_t)blockIdx.x * 256 + threadIdx.x) * 8;
  const int token = (int)(i >> 10);
  const int h = (int)((i >> 6) & 15);
  const float inv =
      1.0f / (Lpart[(size_t)token * HH + h] +
              Lpart[(size_t)4096 * HH + (size_t)token * HH + h]);
  const f16x8 o0 = *(const f16x8*)(Opart + i);
  const f16x8 o1 = *(const f16x8*)(Opart + (size_t)4096 * EE + i);
  f16x8 o;
#pragma unroll
  for (int j = 0; j < 8; ++j)
    o[j] = (f16)(((float)o0[j] + (float)o1[j]) * inv);
  *(f16x8*)(aout + i) = o;
}

// ---------------------------------------------------------------------------
// Workspace layout (45.6 MB, live-range based; no overlap between live bufs):
//   [ 0.0 ..  2.1)  fckT   (transpose2 .. gemm2)
//   [ 2.1 .. 18.9)  qk     (gemm1 .. attn)   -- reused as aoutH after attn
//   [18.9 .. 27.3)  vT     (gemm1 .. attn)
//   [27.3 .. 28.3)  mbits  (pack .. attn)
//   [28.3 .. 28.8)  Lp     (attn .. combine)
//   [28.8 .. 45.6)  scratch: xh(8.4)+Wt(6.3) (prep .. gemm1), then
//                   Opart 16.8 contiguous    (attn .. combine)
// ---------------------------------------------------------------------------
extern "C" void kernel_launch(void* const* d_in, const int* in_sizes, int n_in,
                              void* d_out, int out_size, void* d_ws,
                              size_t ws_size, hipStream_t stream)
{
  (void)in_sizes; (void)n_in; (void)out_size; (void)ws_size;
  const float* x   = (const float*)d_in[0];
  const int* mask  = (const int*)d_in[1];   // jnp bool staged as int32
  const float* wk  = (const float*)d_in[2];
  const float* wb  = (const float*)d_in[3];
  const float* fck = (const float*)d_in[4];
  const float* fcb = (const float*)d_in[5];
  float* out       = (float*)d_out;

  char* ws = (char*)d_ws;
  f16* fckT = (f16*)(ws);                                   //  2,097,152 B
  f16* qk   = (f16*)(ws + 2097152);                         // 16,777,216 B
  f16* vT   = (f16*)(ws + 18874368);                        //  8,388,608 B
  unsigned long long* mbits = (unsigned long long*)(ws + 27262976); // 1 MB
  float* Lp = (float*)(ws + 28311552);                      //    524,288 B
  char* scratch = ws + 28835840;
  f16* xh    = (f16*)scratch;                               //  8,388,608 B
  f16* Wt    = (f16*)(scratch + 8388608);                   //  6,291,456 B
  f16* Opart = (f16*)scratch;                               // 16,777,216 B
  f16* aoutH = qk;                                          // reuse (qk dead)

  // prep
  cvt_f32_f16<<<4096 * 1024 / (8 * 256), 256, 0, stream>>>(x, xh, 4096 * 1024);
  transpose_cvt<<<dim3(3072 / 64, 1024 / 64), 256, 0, stream>>>(wk, Wt, 1024, 3072);
  transpose_cvt<<<dim3(1024 / 64, 1024 / 64), 256, 0, stream>>>(fck, fckT, 1024, 1024);
  pack_mask<<<BB * SS * SS / 256, 256, 0, stream>>>(mask, mbits);

  // qkv = x @ w_kernel + w_bias  (MFMA fp16) -> qk f16 (Q pre-scaled) + vT f16
  gemm_f16<<<dim3(3072 / 128, 4096 / 128), 256, 0, stream>>>(
      xh, Wt, wb, 4096, 3072, 1024, 0, qk, vT, nullptr);

  // key-split attention -> partials (Opart overwrites dead xh/Wt scratch)
  attn_mfma<<<dim3(SS / 128, BB * HH, 2), 256, 0, stream>>>(
      qk, vT, mbits, Opart, Lp);
  combine<<<4096 * 1024 / (8 * 256), 256, 0, stream>>>(Opart, Lp, aoutH);

  // out = aout @ fc_kernel + fc_bias  (MFMA fp16, fp32 out)
  gemm_f16<<<dim3(1024 / 128, 4096 / 128), 256, 0, stream>>>(
      aoutH, fckT, fcb, 4096, 1024, 1024, 1, nullptr, nullptr, out);
}

// Round 11
// 237.536 us; speedup vs baseline: 1.4955x; 1.0241x over previous
//
#include <hip/hip_runtime.h>
#include <math.h>

#define BB 2
#define SS 2048
#define EE 1024
#define HH 16

typedef _Float16 f16;
typedef __attribute__((ext_vector_type(8))) _Float16 f16x8;
typedef __attribute__((ext_vector_type(4))) _Float16 f16x4;
typedef __attribute__((ext_vector_type(2))) _Float16 f16x2;
typedef __attribute__((ext_vector_type(4))) float f32x4;

union P8 { f16x8 v8; f16x2 h2[4]; };
union V8 { f16x8 v8; f16x4 v4[2]; };

// 0.125 (1/sqrt(D)) * log2(e)  -- folded into Q at the GEMM1 epilogue
#define QSCALE 0.18033688011112042f

#if __has_builtin(__builtin_amdgcn_exp2f)
#define EXP2(x) __builtin_amdgcn_exp2f(x)
#else
#define EXP2(x) exp2f(x)
#endif

static __device__ __forceinline__ f16x2 pk2(float a, float b) {
#if __has_builtin(__builtin_amdgcn_cvt_pkrtz)
  return __builtin_bit_cast(f16x2, __builtin_amdgcn_cvt_pkrtz(a, b));
#else
  f16x2 r; r[0] = (f16)a; r[1] = (f16)b; return r;
#endif
}

// async global->LDS, 16B per lane; dest = wave-uniform base + lane*16
static __device__ __forceinline__ void gl16(const void* g, void* l) {
  __builtin_amdgcn_global_load_lds(
      (const __attribute__((address_space(1))) void*)g,
      (__attribute__((address_space(3))) void*)l, 16, 0, 0);
}

// ---------------------------------------------------------------------------
// Fused prep: [0,2048) cvt x->f16 | [2048,2816) wk^T | [2816,3072) fck^T |
// [3072,11264) pack mask bits. Block-uniform branches.
// ---------------------------------------------------------------------------
__global__ __launch_bounds__(256) void prep(
    const float* __restrict__ x, f16* __restrict__ xh,
    const float* __restrict__ wk, f16* __restrict__ Wt,
    const float* __restrict__ fck, f16* __restrict__ fckT,
    const int* __restrict__ mask, unsigned long long* __restrict__ mbits)
{
  const int bid = blockIdx.x;
  const int tid = threadIdx.x;
  __shared__ float T[64][65];

  if (bid < 2048) {                       // x (f32) -> xh (f16), 8/thread
    const int i = (bid * 256 + tid) * 8;
    float4 a = *(const float4*)(x + i);
    float4 b = *(const float4*)(x + i + 4);
    f16x8 o;
    o[0] = (f16)a.x; o[1] = (f16)a.y; o[2] = (f16)a.z; o[3] = (f16)a.w;
    o[4] = (f16)b.x; o[5] = (f16)b.y; o[6] = (f16)b.z; o[7] = (f16)b.w;
    *(f16x8*)(xh + i) = o;
    return;
  }
  if (bid < 3072) {                       // transpose+cvt: out[n][k]=in[k][n]
    const float* in; f16* outp; int K, N, bx, by;
    if (bid < 2816) {
      const int lb = bid - 2048;          // wk: K=1024, N=3072, 48x16 blocks
      bx = lb % 48; by = lb / 48; in = wk; outp = Wt; K = 1024; N = 3072;
    } else {
      const int lb = bid - 2816;          // fck: 16x16 blocks
      bx = lb & 15; by = lb >> 4; in = fck; outp = fckT; K = 1024; N = 1024;
    }
    const int k0 = by * 64, n0 = bx * 64;
    const int tr = tid >> 4, tc = (tid & 15) * 4;
#pragma unroll
    for (int i = 0; i < 4; ++i) {
      int r = tr + i * 16;
      *(float4*)&T[r][tc] = *(const float4*)(in + (size_t)(k0 + r) * N + n0 + tc);
    }
    __syncthreads();
#pragma unroll
    for (int i = 0; i < 4; ++i) {
      int nl = tr + i * 16;
      f16x4 v;
      v[0] = (f16)T[tc + 0][nl];
      v[1] = (f16)T[tc + 1][nl];
      v[2] = (f16)T[tc + 2][nl];
      v[3] = (f16)T[tc + 3][nl];
      *(f16x4*)(outp + (size_t)(n0 + nl) * K + k0 + tc) = v;
    }
    return;
  }
  // pack mask (int32, nonzero = masked) -> bitmask; wave handles 256 ints
  const int lb = bid - 3072;
  const int wg = lb * 4 + (tid >> 6);
  const int lane = tid & 63;
  const size_t base = (size_t)wg * 256;
#pragma unroll
  for (int k = 0; k < 4; ++k) {
    const unsigned long long bal = __ballot(mask[base + k * 64 + lane] != 0);
    if (lane == 0) mbits[(base >> 6) + k] = bal;
  }
}

// ---------------------------------------------------------------------------
// GEMM1 (qkv): 128x128 tile, BK=32, global_load_lds w16, both-sides XOR
// chunk swizzle. Epilogue: Q/K blocks staged through LDS -> coalesced f16x8
// stores (Q pre-scaled by QSCALE); V blocks -> vT packed f16x4 (as before).
// ---------------------------------------------------------------------------
__global__ __launch_bounds__(256) void gemm_qkv(
    const f16* __restrict__ A, const f16* __restrict__ Bt,
    const float* __restrict__ bias,
    f16* __restrict__ oQK, f16* __restrict__ oVT)
{
  __shared__ f16 SH[8192];                // Ah = [0,4096), Bh = [4096,8192)
  f16* Ah = SH;
  f16* Bh = SH + 4096;
  const int K = 1024;

  const int t = threadIdx.x;
  const int l = t & 63, w = t >> 6;
  const int l15 = l & 15, l4 = l >> 4;
  const int wr = w >> 1, wc = w & 1;
  const int n0 = blockIdx.x * 128, m0 = blockIdx.y * 128;

  const int srow = l >> 2;
  const int gch  = (l & 3) ^ (srow & 3);
  const f16* Ap0 = A + (size_t)(m0 + w * 32 + srow) * K + gch * 8;
  const f16* Ap1 = Ap0 + (size_t)16 * K;
  const f16* Bp0 = Bt + (size_t)(n0 + w * 32 + srow) * K + gch * 8;
  const f16* Bp1 = Bp0 + (size_t)16 * K;
  f16* ldsA0 = &Ah[(w * 32) * 32];
  f16* ldsA1 = &Ah[(w * 32 + 16) * 32];
  f16* ldsB0 = &Bh[(w * 32) * 32];
  f16* ldsB1 = &Bh[(w * 32 + 16) * 32];

  f32x4 acc[4][4] = {};
  const int csw = (l15 & 3);

  for (int k0 = 0; k0 < K; k0 += 32) {
    gl16(Ap0 + k0, ldsA0);
    gl16(Ap1 + k0, ldsA1);
    gl16(Bp0 + k0, ldsB0);
    gl16(Bp1 + k0, ldsB1);
    __syncthreads();

    f16x8 af[4], bf[4];
#pragma unroll
    for (int mr = 0; mr < 4; ++mr) {
      const int row = wr * 64 + mr * 16 + l15;
      af[mr] = *(const f16x8*)&Ah[row * 32 + ((l4 ^ csw) * 8)];
    }
#pragma unroll
    for (int nr = 0; nr < 4; ++nr) {
      const int row = wc * 64 + nr * 16 + l15;
      bf[nr] = *(const f16x8*)&Bh[row * 32 + ((l4 ^ csw) * 8)];
    }
    __builtin_amdgcn_s_setprio(1);
#pragma unroll
    for (int mr = 0; mr < 4; ++mr)
#pragma unroll
      for (int nr = 0; nr < 4; ++nr)
        acc[mr][nr] = __builtin_amdgcn_mfma_f32_16x16x32_f16(
            af[mr], bf[nr], acc[mr][nr], 0, 0, 0);
    __builtin_amdgcn_s_setprio(0);
    __syncthreads();
  }

  if (n0 < 2048) {
    // LDS-staged coalesced epilogue, two 64-row halves (16 KB each).
    const float qs = (n0 < 1024) ? QSCALE : 1.0f;
#pragma unroll
    for (int half = 0; half < 2; ++half) {
      __syncthreads();
      if (wr == half) {
#pragma unroll
        for (int nr = 0; nr < 4; ++nr) {
          const int col = wc * 64 + nr * 16 + l15;
          const float bv = bias[n0 + col];
#pragma unroll
          for (int mr = 0; mr < 4; ++mr)
#pragma unroll
            for (int j = 0; j < 4; ++j) {
              const int r = mr * 16 + l4 * 4 + j;
              SH[r * 128 + ((((col >> 3) ^ (r & 15)) << 3) | (col & 7))] =
                  (f16)((acc[mr][nr][j] + bv) * qs);
            }
        }
      }
      __syncthreads();
#pragma unroll
      for (int cc = 0; cc < 4; ++cc) {
        const int row = w * 16 + cc * 4 + (l >> 4);
        const int ch  = l & 15;
        const f16x8 v =
            *(const f16x8*)&SH[row * 128 + ((ch ^ (row & 15)) << 3)];
        *(f16x8*)(oQK + (size_t)(m0 + half * 64 + row) * 2048 + n0 + ch * 8) = v;
      }
    }
  } else {
#pragma unroll
    for (int nr = 0; nr < 4; ++nr) {
      const int n = n0 + wc * 64 + nr * 16 + l15;
      const float bv = bias[n];
      const int hh = (n - 2048) >> 6;
      const int d = (n - 2048) & 63;
#pragma unroll
      for (int mr = 0; mr < 4; ++mr) {
        const int tok0 = m0 + wr * 64 + mr * 16 + l4 * 4;
        const int bq = tok0 >> 11, sq = tok0 & 2047;
        f16x4 v;
        v[0] = (f16)(acc[mr][nr][0] + bv);
        v[1] = (f16)(acc[mr][nr][1] + bv);
        v[2] = (f16)(acc[mr][nr][2] + bv);
        v[3] = (f16)(acc[mr][nr][3] + bv);
        *(f16x4*)(oVT + ((size_t)(bq * 16 + hh) * 64 + d) * SS + sq) = v;
      }
    }
  }
}

// ---------------------------------------------------------------------------
// GEMM2 (fc): 128x64 tile, grid (16,32)=512 blocks = 2/CU. fp32 out + bias.
// ---------------------------------------------------------------------------
__global__ __launch_bounds__(256) void gemm_fc(
    const f16* __restrict__ A, const f16* __restrict__ Bt,
    const float* __restrict__ bias, float* __restrict__ outF)
{
  __shared__ f16 Ah[128 * 32];
  __shared__ f16 Bh[64 * 32];
  const int K = 1024, N = 1024;

  const int t = threadIdx.x;
  const int l = t & 63, w = t >> 6;
  const int l15 = l & 15, l4 = l >> 4;
  const int wr = w >> 1, wc = w & 1;
  const int n0 = blockIdx.x * 64, m0 = blockIdx.y * 128;

  const int srow = l >> 2;
  const int gch  = (l & 3) ^ (srow & 3);
  const f16* Ap0 = A + (size_t)(m0 + w * 32 + srow) * K + gch * 8;
  const f16* Ap1 = Ap0 + (size_t)16 * K;
  const f16* Bp0 = Bt + (size_t)(n0 + w * 16 + srow) * K + gch * 8;
  f16* ldsA0 = &Ah[(w * 32) * 32];
  f16* ldsA1 = &Ah[(w * 32 + 16) * 32];
  f16* ldsB0 = &Bh[(w * 16) * 32];

  f32x4 acc[4][2] = {};
  const int csw = (l15 & 3);

  for (int k0 = 0; k0 < K; k0 += 32) {
    gl16(Ap0 + k0, ldsA0);
    gl16(Ap1 + k0, ldsA1);
    gl16(Bp0 + k0, ldsB0);
    __syncthreads();

    f16x8 af[4], bf[2];
#pragma unroll
    for (int mr = 0; mr < 4; ++mr) {
      const int row = wr * 64 + mr * 16 + l15;
      af[mr] = *(const f16x8*)&Ah[row * 32 + ((l4 ^ csw) * 8)];
    }
#pragma unroll
    for (int nr = 0; nr < 2; ++nr) {
      const int row = wc * 32 + nr * 16 + l15;
      bf[nr] = *(const f16x8*)&Bh[row * 32 + ((l4 ^ csw) * 8)];
    }
    __builtin_amdgcn_s_setprio(1);
#pragma unroll
    for (int mr = 0; mr < 4; ++mr)
#pragma unroll
      for (int nr = 0; nr < 2; ++nr)
        acc[mr][nr] = __builtin_amdgcn_mfma_f32_16x16x32_f16(
            af[mr], bf[nr], acc[mr][nr], 0, 0, 0);
    __builtin_amdgcn_s_setprio(0);
    __syncthreads();
  }

#pragma unroll
  for (int nr = 0; nr < 2; ++nr) {
    const int n = n0 + wc * 32 + nr * 16 + l15;
    const float bv = bias[n];
#pragma unroll
    for (int mr = 0; mr < 4; ++mr)
#pragma unroll
      for (int j = 0; j < 4; ++j) {
        const int m = m0 + wr * 64 + mr * 16 + l4 * 4 + j;
        outF[(size_t)m * N + n] = acc[mr][nr][j] + bv;
      }
  }
}

// ---------------------------------------------------------------------------
// MFMA attention (unchanged from round 10: 61.4 us measured).
// ---------------------------------------------------------------------------
#define VPAD 36
__global__ __launch_bounds__(256, 4) void attn_mfma(
    const f16* __restrict__ qkbuf, const f16* __restrict__ vT,
    const unsigned long long* __restrict__ mbits,
    f16* __restrict__ Opart, float* __restrict__ Lpart)
{
  __shared__ f16 Kds[2][32 * 64];     // [key][d], chunk-swizzled, 8 KB
  __shared__ f16 Vds[2][64 * VPAD];   // [d][key+pad], 9 KB

  const int t = threadIdx.x;
  const int w = t >> 6, l = t & 63, l15 = l & 15, l4 = l >> 4;
  const int bh = blockIdx.y, b = bh >> 4, h = bh & 15;
  const int ks = blockIdx.z;
  const int qbase = blockIdx.x * 128 + w * 32;

  f16x8 q00, q01, q10, q11;
  {
    const size_t r0 = (size_t)(b * SS + qbase + l15) * 2048 + h * 64;
    const size_t r1 = (size_t)(b * SS + qbase + 16 + l15) * 2048 + h * 64;
    q00 = *(const f16x8*)(qkbuf + r0 + l4 * 8);
    q01 = *(const f16x8*)(qkbuf + r0 + 32 + l4 * 8);
    q10 = *(const f16x8*)(qkbuf + r1 + l4 * 8);
    q11 = *(const f16x8*)(qkbuf + r1 + 32 + l4 * 8);
  }

  f32x4 accA[4] = {}, accB[4] = {};
  f32x4 accLA = {}, accLB = {};
  f16x8 ones;
#pragma unroll
  for (int i = 0; i < 8; ++i) ones[i] = (f16)1.0f;

  const unsigned int* mA =
      (const unsigned int*)mbits + (size_t)(b * SS + qbase + l15) * 64 + ks * 32;
  const unsigned int* mB =
      (const unsigned int*)mbits + (size_t)(b * SS + qbase + 16 + l15) * 64 + ks * 32;

  const int srow = t >> 3;
  const int scb  = (t & 7) * 8;
  const int sws  = (srow & 7) << 3;
  const f16* kb = qkbuf + (size_t)b * SS * 2048 + 1024 + h * 64 + scb +
                  (size_t)ks * 1024 * 2048;
  const int vd  = t >> 2;
  const int vkb = (t & 3) * 8;
  const f16* vb = vT + ((size_t)bh * 64 + vd) * SS + ks * 1024 + vkb;

  f16x8 kr0; V8 vr0;
#define LOADT(kt)                                                         \
  {                                                                       \
    kr0 = *(const f16x8*)(kb + (size_t)((kt) + srow) * 2048);             \
    vr0.v8 = *(const f16x8*)(vb + (kt));                                  \
  }
#define COMMIT(bi)                                                        \
  {                                                                       \
    *(f16x8*)&Kds[bi][srow * 64 + (scb ^ sws)] = kr0;                     \
    *(f16x4*)&Vds[bi][vd * VPAD + vkb]     = vr0.v4[0];                   \
    *(f16x4*)&Vds[bi][vd * VPAD + vkb + 4] = vr0.v4[1];                   \
  }

  LOADT(0)
  COMMIT(0)
  LOADT(32)
  __syncthreads();

  const int swr = (l15 & 7) << 3;

#define BODY(cur, tI)                                                         \
  {                                                                           \
    const unsigned int mbA = mA[tI];                                          \
    const unsigned int mbB = mB[tI];                                          \
    float pA[8], pB[8];                                                       \
    _Pragma("unroll")                                                         \
    for (int g = 0; g < 2; ++g) {                                             \
      const f16* krow = &Kds[cur][(g * 16 + l15) * 64];                       \
      const f16x8 k0 = *(const f16x8*)(krow + ((l4 * 8) ^ swr));              \
      const f16x8 k1 = *(const f16x8*)(krow + ((32 + l4 * 8) ^ swr));         \
      __builtin_amdgcn_s_setprio(1);                                          \
      f32x4 SA = __builtin_amdgcn_mfma_f32_16x16x32_f16(                      \
          k0, q00, (f32x4){0.f, 0.f, 0.f, 0.f}, 0, 0, 0);                     \
      SA = __builtin_amdgcn_mfma_f32_16x16x32_f16(k1, q01, SA, 0, 0, 0);      \
      f32x4 SB = __builtin_amdgcn_mfma_f32_16x16x32_f16(                      \
          k0, q10, (f32x4){0.f, 0.f, 0.f, 0.f}, 0, 0, 0);                     \
      SB = __builtin_amdgcn_mfma_f32_16x16x32_f16(k1, q11, SB, 0, 0, 0);      \
      __builtin_amdgcn_s_setprio(0);                                          \
      const unsigned int nibA = mbA >> (g * 16 + l4 * 4);                     \
      const unsigned int nibB = mbB >> (g * 16 + l4 * 4);                     \
      _Pragma("unroll")                                                       \
      for (int j = 0; j < 4; ++j) {                                           \
        pA[g * 4 + j] = ((nibA >> j) & 1u) ? 1.0f : EXP2(SA[j]);              \
        pB[g * 4 + j] = ((nibB >> j) & 1u) ? 1.0f : EXP2(SB[j]);              \
      }                                                                       \
    }                                                                         \
    P8 uA, uB;                                                                \
    uA.h2[0] = pk2(pA[0], pA[1]); uA.h2[1] = pk2(pA[2], pA[3]);               \
    uA.h2[2] = pk2(pA[4], pA[5]); uA.h2[3] = pk2(pA[6], pA[7]);               \
    uB.h2[0] = pk2(pB[0], pB[1]); uB.h2[1] = pk2(pB[2], pB[3]);               \
    uB.h2[2] = pk2(pB[4], pB[5]); uB.h2[3] = pk2(pB[6], pB[7]);               \
    __builtin_amdgcn_s_setprio(1);                                            \
    _Pragma("unroll")                                                         \
    for (int dg = 0; dg < 4; ++dg) {                                          \
      const f16* vrow = &Vds[cur][(dg * 16 + l15) * VPAD];                    \
      V8 uv;                                                                  \
      uv.v4[0] = *(const f16x4*)(vrow + l4 * 4);                              \
      uv.v4[1] = *(const f16x4*)(vrow + 16 + l4 * 4);                         \
      accA[dg] = __builtin_amdgcn_mfma_f32_16x16x32_f16(uA.v8, uv.v8,         \
                                                        accA[dg], 0, 0, 0);   \
      accB[dg] = __builtin_amdgcn_mfma_f32_16x16x32_f16(uB.v8, uv.v8,         \
                                                        accB[dg], 0, 0, 0);   \
    }                                                                         \
    accLA = __builtin_amdgcn_mfma_f32_16x16x32_f16(uA.v8, ones, accLA,        \
                                                   0, 0, 0);                  \
    accLB = __builtin_amdgcn_mfma_f32_16x16x32_f16(uB.v8, ones, accLB,        \
                                                   0, 0, 0);                  \
    __builtin_amdgcn_s_setprio(0);                                            \
    if ((tI) + 1 < 32) {                                                      \
      COMMIT((cur) ^ 1)                                                       \
      if ((tI) + 2 < 32) LOADT(((tI) + 2) * 32)                               \
    }                                                                         \
    __syncthreads();                                                          \
  }

  for (int tI = 0; tI < 32; tI += 2) {
    BODY(0, tI)
    BODY(1, tI + 1)
  }

  const size_t obase = (size_t)ks * 4096 * EE;
#pragma unroll
  for (int j = 0; j < 4; ++j) {
    const int qr = l4 * 4 + j;
    const size_t rowA = (size_t)(b * SS + qbase + qr) * EE + h * 64 + l15;
    const size_t rowB = (size_t)(b * SS + qbase + 16 + qr) * EE + h * 64 + l15;
#pragma unroll
    for (int dg = 0; dg < 4; ++dg) {
      Opart[obase + rowA + dg * 16] = (f16)accA[dg][j];
      Opart[obase + rowB + dg * 16] = (f16)accB[dg][j];
    }
    if (l15 == 0) {
      Lpart[(size_t)ks * 4096 * HH + (size_t)(b * SS + qbase + qr) * HH + h] =
          accLA[j];
      Lpart[(size_t)ks * 4096 * HH +
            (size_t)(b * SS + qbase + 16 + qr) * HH + h] = accLB[j];
    }
  }
}

// ---------------------------------------------------------------------------
// combine: aout = (O0 + O1) / (L0 + L1), f16 out. 8 elems/thread.
// ---------------------------------------------------------------------------
__global__ __launch_bounds__(256) void combine(
    const f16* __restrict__ Opart, const float* __restrict__ Lpart,
    f16* __restrict__ aout)
{
  const size_t i = ((size_t)blockIdx.x * 256 + threadIdx.x) * 8;
  const int token = (int)(i >> 10);
  const int h = (int)((i >> 6) & 15);
  const float inv =
      1.0f / (Lpart[(size_t)token * HH + h] +
              Lpart[(size_t)4096 * HH + (size_t)token * HH + h]);
  const f16x8 o0 = *(const f16x8*)(Opart + i);
  const f16x8 o1 = *(const f16x8*)(Opart + (size_t)4096 * EE + i);
  f16x8 o;
#pragma unroll
  for (int j = 0; j < 8; ++j)
    o[j] = (f16)(((float)o0[j] + (float)o1[j]) * inv);
  *(f16x8*)(aout + i) = o;
}

// ---------------------------------------------------------------------------
// Workspace layout (45.6 MB, live-range based; no overlap between live bufs):
//   [ 0.0 ..  2.1)  fckT   (prep .. gemm_fc)
//   [ 2.1 .. 18.9)  qk     (gemm_qkv .. attn)  -- reused as aoutH after attn
//   [18.9 .. 27.3)  vT     (gemm_qkv .. attn)
//   [27.3 .. 28.3)  mbits  (prep .. attn)
//   [28.3 .. 28.8)  Lp     (attn .. combine)
//   [28.8 .. 45.6)  scratch: xh(8.4)+Wt(6.3) (prep .. gemm_qkv), then
//                   Opart 16.8 contiguous    (attn .. combine)
// ---------------------------------------------------------------------------
extern "C" void kernel_launch(void* const* d_in, const int* in_sizes, int n_in,
                              void* d_out, int out_size, void* d_ws,
                              size_t ws_size, hipStream_t stream)
{
  (void)in_sizes; (void)n_in; (void)out_size; (void)ws_size;
  const float* x   = (const float*)d_in[0];
  const int* mask  = (const int*)d_in[1];   // jnp bool staged as int32
  const float* wk  = (const float*)d_in[2];
  const float* wb  = (const float*)d_in[3];
  const float* fck = (const float*)d_in[4];
  const float* fcb = (const float*)d_in[5];
  float* out       = (float*)d_out;

  char* ws = (char*)d_ws;
  f16* fckT = (f16*)(ws);                                   //  2,097,152 B
  f16* qk   = (f16*)(ws + 2097152);                         // 16,777,216 B
  f16* vT   = (f16*)(ws + 18874368);                        //  8,388,608 B
  unsigned long long* mbits = (unsigned long long*)(ws + 27262976); // 1 MB
  float* Lp = (float*)(ws + 28311552);                      //    524,288 B
  char* scratch = ws + 28835840;
  f16* xh    = (f16*)scratch;                               //  8,388,608 B
  f16* Wt    = (f16*)(scratch + 8388608);                   //  6,291,456 B
  f16* Opart = (f16*)scratch;                               // 16,777,216 B
  f16* aoutH = qk;                                          // reuse (qk dead)

  // fused prep: cvt x | wk^T | fck^T | pack mask
  prep<<<11264, 256, 0, stream>>>(x, xh, wk, Wt, fck, fckT, mask, mbits);

  // qkv = x @ w_kernel + w_bias -> qk f16 (Q pre-scaled) + vT f16
  gemm_qkv<<<dim3(3072 / 128, 4096 / 128), 256, 0, stream>>>(
      xh, Wt, wb, qk, vT);

  // key-split attention -> partials (Opart overwrites dead xh/Wt scratch)
  attn_mfma<<<dim3(SS / 128, BB * HH, 2), 256, 0, stream>>>(
      qk, vT, mbits, Opart, Lp);
  combine<<<4096 * 1024 / (8 * 256), 256, 0, stream>>>(Opart, Lp, aoutH);

  // out = aout @ fc_kernel + fc_bias (fp32 out)
  gemm_fc<<<dim3(1024 / 64, 4096 / 128), 256, 0, stream>>>(
      aoutH, fckT, fcb, out);
}

// Round 12
// 233.932 us; speedup vs baseline: 1.5185x; 1.0154x over previous
//
#include <hip/hip_runtime.h>
#include <math.h>

#define BB 2
#define SS 2048
#define EE 1024
#define HH 16

typedef _Float16 f16;
typedef __attribute__((ext_vector_type(8))) _Float16 f16x8;
typedef __attribute__((ext_vector_type(4))) _Float16 f16x4;
typedef __attribute__((ext_vector_type(2))) _Float16 f16x2;
typedef __attribute__((ext_vector_type(4))) float f32x4;

union P8 { f16x8 v8; f16x2 h2[4]; };
union V8 { f16x8 v8; f16x4 v4[2]; };

// 0.125 (1/sqrt(D)) * log2(e)  -- folded into Q at the GEMM1 epilogue
#define QSCALE 0.18033688011112042f

#if __has_builtin(__builtin_amdgcn_exp2f)
#define EXP2(x) __builtin_amdgcn_exp2f(x)
#else
#define EXP2(x) exp2f(x)
#endif

static __device__ __forceinline__ f16x2 pk2(float a, float b) {
#if __has_builtin(__builtin_amdgcn_cvt_pkrtz)
  return __builtin_bit_cast(f16x2, __builtin_amdgcn_cvt_pkrtz(a, b));
#else
  f16x2 r; r[0] = (f16)a; r[1] = (f16)b; return r;
#endif
}

// async global->LDS, 16B per lane; dest = wave-uniform base + lane*16
static __device__ __forceinline__ void gl16(const void* g, void* l) {
  __builtin_amdgcn_global_load_lds(
      (const __attribute__((address_space(1))) void*)g,
      (__attribute__((address_space(3))) void*)l, 16, 0, 0);
}

// ---------------------------------------------------------------------------
// Fused prep: [0,2048) cvt x->f16 | [2048,2816) wk^T | [2816,3072) fck^T |
// [3072,11264) pack mask bits. Block-uniform branches.
// ---------------------------------------------------------------------------
__global__ __launch_bounds__(256) void prep(
    const float* __restrict__ x, f16* __restrict__ xh,
    const float* __restrict__ wk, f16* __restrict__ Wt,
    const float* __restrict__ fck, f16* __restrict__ fckT,
    const int* __restrict__ mask, unsigned long long* __restrict__ mbits)
{
  const int bid = blockIdx.x;
  const int tid = threadIdx.x;
  __shared__ float T[64][65];

  if (bid < 2048) {                       // x (f32) -> xh (f16), 8/thread
    const int i = (bid * 256 + tid) * 8;
    float4 a = *(const float4*)(x + i);
    float4 b = *(const float4*)(x + i + 4);
    f16x8 o;
    o[0] = (f16)a.x; o[1] = (f16)a.y; o[2] = (f16)a.z; o[3] = (f16)a.w;
    o[4] = (f16)b.x; o[5] = (f16)b.y; o[6] = (f16)b.z; o[7] = (f16)b.w;
    *(f16x8*)(xh + i) = o;
    return;
  }
  if (bid < 3072) {                       // transpose+cvt: out[n][k]=in[k][n]
    const float* in; f16* outp; int K, N, bx, by;
    if (bid < 2816) {
      const int lb = bid - 2048;          // wk: K=1024, N=3072, 48x16 blocks
      bx = lb % 48; by = lb / 48; in = wk; outp = Wt; K = 1024; N = 3072;
    } else {
      const int lb = bid - 2816;          // fck: 16x16 blocks
      bx = lb & 15; by = lb >> 4; in = fck; outp = fckT; K = 1024; N = 1024;
    }
    const int k0 = by * 64, n0 = bx * 64;
    const int tr = tid >> 4, tc = (tid & 15) * 4;
#pragma unroll
    for (int i = 0; i < 4; ++i) {
      int r = tr + i * 16;
      *(float4*)&T[r][tc] = *(const float4*)(in + (size_t)(k0 + r) * N + n0 + tc);
    }
    __syncthreads();
#pragma unroll
    for (int i = 0; i < 4; ++i) {
      int nl = tr + i * 16;
      f16x4 v;
      v[0] = (f16)T[tc + 0][nl];
      v[1] = (f16)T[tc + 1][nl];
      v[2] = (f16)T[tc + 2][nl];
      v[3] = (f16)T[tc + 3][nl];
      *(f16x4*)(outp + (size_t)(n0 + nl) * K + k0 + tc) = v;
    }
    return;
  }
  // pack mask (int32, nonzero = masked) -> bitmask; wave handles 256 ints
  const int lb = bid - 3072;
  const int wg = lb * 4 + (tid >> 6);
  const int lane = tid & 63;
  const size_t base = (size_t)wg * 256;
#pragma unroll
  for (int k = 0; k < 4; ++k) {
    const unsigned long long bal = __ballot(mask[base + k * 64 + lane] != 0);
    if (lane == 0) mbits[(base >> 6) + k] = bal;
  }
}

// ---------------------------------------------------------------------------
// GEMM1 (qkv): 128x128 tile, BK=32, 2-PHASE double-buffered gl16 staging
// (stage t+1 issued BEFORE compute t; ONE barrier per K-step), XCD-swizzled
// grid. Epilogues: Q/K LDS-staged coalesced f16x8 (Q pre-scaled by QSCALE);
// V transposed through LDS -> coalesced f16x8 stores along tokens.
// ---------------------------------------------------------------------------
__global__ __launch_bounds__(256) void gemm_qkv(
    const f16* __restrict__ A, const f16* __restrict__ Bt,
    const float* __restrict__ bias,
    f16* __restrict__ oQK, f16* __restrict__ oVT)
{
  __shared__ f16 SH[16384];   // 32KB: A bufs [0,4096),[4096,8192); B at +8192

  const int K = 1024;
  const int t = threadIdx.x;
  const int l = t & 63, w = t >> 6;
  const int l15 = l & 15, l4 = l >> 4;
  const int wr = w >> 1, wc = w & 1;

  // XCD-aware bijective swizzle: 768 blocks, 96 per XCD = 4 full m-rows.
  const int bid = blockIdx.x;
  const int swz = (bid & 7) * 96 + (bid >> 3);
  const int bx = swz % 24, by = swz / 24;
  const int n0 = bx * 128, m0 = by * 128;

  const int srow = l >> 2;
  const int gch  = (l & 3) ^ (srow & 3);
  const f16* Ap0 = A + (size_t)(m0 + w * 32 + srow) * K + gch * 8;
  const f16* Ap1 = Ap0 + (size_t)16 * K;
  const f16* Bp0 = Bt + (size_t)(n0 + w * 32 + srow) * K + gch * 8;
  const f16* Bp1 = Bp0 + (size_t)16 * K;
  const int offA0 = (w * 32) * 32, offA1 = (w * 32 + 16) * 32;

  f32x4 acc[4][4] = {};
  const int csw = (l15 & 3);

#define QSTAGE(bi, kt)                                                    \
  {                                                                       \
    f16* ab = SH + (bi) * 4096;                                           \
    f16* bb = SH + 8192 + (bi) * 4096;                                    \
    gl16(Ap0 + (kt) * 32, ab + offA0);                                    \
    gl16(Ap1 + (kt) * 32, ab + offA1);                                    \
    gl16(Bp0 + (kt) * 32, bb + offA0);                                    \
    gl16(Bp1 + (kt) * 32, bb + offA1);                                    \
  }

#define QITER(bi, kt)                                                     \
  {                                                                       \
    if ((kt) + 1 < 32) QSTAGE((bi) ^ 1, (kt) + 1)                         \
    const f16* ab = SH + (bi) * 4096;                                     \
    const f16* bb = SH + 8192 + (bi) * 4096;                              \
    f16x8 af[4], bf[4];                                                   \
    _Pragma("unroll")                                                     \
    for (int mr = 0; mr < 4; ++mr)                                        \
      af[mr] = *(const f16x8*)&ab[(wr * 64 + mr * 16 + l15) * 32 +        \
                                  ((l4 ^ csw) * 8)];                      \
    _Pragma("unroll")                                                     \
    for (int nr = 0; nr < 4; ++nr)                                        \
      bf[nr] = *(const f16x8*)&bb[(wc * 64 + nr * 16 + l15) * 32 +        \
                                  ((l4 ^ csw) * 8)];                      \
    __builtin_amdgcn_s_setprio(1);                                        \
    _Pragma("unroll")                                                     \
    for (int mr = 0; mr < 4; ++mr)                                        \
      _Pragma("unroll")                                                   \
      for (int nr = 0; nr < 4; ++nr)                                      \
        acc[mr][nr] = __builtin_amdgcn_mfma_f32_16x16x32_f16(             \
            af[mr], bf[nr], acc[mr][nr], 0, 0, 0);                        \
    __builtin_amdgcn_s_setprio(0);                                        \
    __syncthreads();                                                      \
  }

  QSTAGE(0, 0)
  __syncthreads();
  for (int kt = 0; kt < 32; kt += 2) {
    QITER(0, kt)
    QITER(1, kt + 1)
  }
  // final loop barrier: all ds_reads done -> LDS reusable for epilogue

  if (n0 < 2048) {
    // LDS-staged coalesced epilogue, two 64-row halves (16 KB each).
    const float qs = (n0 < 1024) ? QSCALE : 1.0f;
#pragma unroll
    for (int half = 0; half < 2; ++half) {
      if (half) __syncthreads();
      if (wr == half) {
#pragma unroll
        for (int nr = 0; nr < 4; ++nr) {
          const int col = wc * 64 + nr * 16 + l15;
          const float bv = bias[n0 + col];
#pragma unroll
          for (int mr = 0; mr < 4; ++mr)
#pragma unroll
            for (int j = 0; j < 4; ++j) {
              const int r = mr * 16 + l4 * 4 + j;
              SH[r * 128 + ((((col >> 3) ^ (r & 15)) << 3) | (col & 7))] =
                  (f16)((acc[mr][nr][j] + bv) * qs);
            }
        }
      }
      __syncthreads();
#pragma unroll
      for (int cc = 0; cc < 4; ++cc) {
        const int row = w * 16 + cc * 4 + (l >> 4);
        const int ch  = l & 15;
        const f16x8 v =
            *(const f16x8*)&SH[row * 128 + ((ch ^ (row & 15)) << 3)];
        *(f16x8*)(oQK + (size_t)(m0 + half * 64 + row) * 2048 + n0 + ch * 8) = v;
      }
    }
  } else {
    // V: transpose-stage [col][token] in LDS -> coalesced stores along tokens
    const int vbase = n0 - 2048;            // multiple of 128
    const int bq = m0 >> 11, sq0 = m0 & 2047;
#pragma unroll
    for (int half = 0; half < 2; ++half) {
      if (half) __syncthreads();
      if (wc == half) {
#pragma unroll
        for (int nr = 0; nr < 4; ++nr) {
          const int colh = nr * 16 + l15;   // 0..63 within half
          const float bv = bias[2048 + vbase + half * 64 + colh];
#pragma unroll
          for (int mr = 0; mr < 4; ++mr)
#pragma unroll
            for (int j = 0; j < 4; ++j) {
              const int tok = wr * 64 + mr * 16 + l4 * 4 + j;
              SH[colh * 136 + tok] = (f16)(acc[mr][nr][j] + bv);
            }
        }
      }
      __syncthreads();
      // 64 cols x 16 token-chunks = 1024 units; 4 per thread; 16 lanes of a
      // group share a col -> 256B contiguous store runs (coalesced).
#pragma unroll
      for (int u = 0; u < 4; ++u) {
        const int unit = u * 256 + t;
        const int colh = unit >> 4, ch = unit & 15;
        const f16x8 v = *(const f16x8*)&SH[colh * 136 + ch * 8];
        const int nloc = vbase + half * 64 + colh;
        const int hh = nloc >> 6, d = nloc & 63;
        *(f16x8*)(oVT + ((size_t)(bq * 16 + hh) * 64 + d) * SS + sq0 + ch * 8) = v;
      }
    }
  }
}

// ---------------------------------------------------------------------------
// GEMM2 (fc): 128x64 tile, 2-phase double-buffered, XCD-swizzled 512 grid.
// fp32 out + bias.
// ---------------------------------------------------------------------------
__global__ __launch_bounds__(256) void gemm_fc(
    const f16* __restrict__ A, const f16* __restrict__ Bt,
    const float* __restrict__ bias, float* __restrict__ outF)
{
  __shared__ f16 SH2[12288];  // 24KB: A bufs [0,4096),[4096,8192); B at +8192

  const int K = 1024, N = 1024;
  const int t = threadIdx.x;
  const int l = t & 63, w = t >> 6;
  const int l15 = l & 15, l4 = l >> 4;
  const int wr = w >> 1, wc = w & 1;

  const int bid = blockIdx.x;
  const int swz = (bid & 7) * 64 + (bid >> 3);
  const int bx = swz & 15, by = swz >> 4;
  const int n0 = bx * 64, m0 = by * 128;

  const int srow = l >> 2;
  const int gch  = (l & 3) ^ (srow & 3);
  const f16* Ap0 = A + (size_t)(m0 + w * 32 + srow) * K + gch * 8;
  const f16* Ap1 = Ap0 + (size_t)16 * K;
  const f16* Bp0 = Bt + (size_t)(n0 + w * 16 + srow) * K + gch * 8;
  const int offA0 = (w * 32) * 32, offA1 = (w * 32 + 16) * 32;
  const int offB0 = (w * 16) * 32;

  f32x4 acc[4][2] = {};
  const int csw = (l15 & 3);

#define FSTAGE(bi, kt)                                                    \
  {                                                                       \
    f16* ab = SH2 + (bi) * 4096;                                          \
    f16* bb = SH2 + 8192 + (bi) * 2048;                                   \
    gl16(Ap0 + (kt) * 32, ab + offA0);                                    \
    gl16(Ap1 + (kt) * 32, ab + offA1);                                    \
    gl16(Bp0 + (kt) * 32, bb + offB0);                                    \
  }

#define FITER(bi, kt)                                                     \
  {                                                                       \
    if ((kt) + 1 < 32) FSTAGE((bi) ^ 1, (kt) + 1)                         \
    const f16* ab = SH2 + (bi) * 4096;                                    \
    const f16* bb = SH2 + 8192 + (bi) * 2048;                             \
    f16x8 af[4], bf[2];                                                   \
    _Pragma("unroll")                                                     \
    for (int mr = 0; mr < 4; ++mr)                                        \
      af[mr] = *(const f16x8*)&ab[(wr * 64 + mr * 16 + l15) * 32 +        \
                                  ((l4 ^ csw) * 8)];                      \
    _Pragma("unroll")                                                     \
    for (int nr = 0; nr < 2; ++nr)                                        \
      bf[nr] = *(const f16x8*)&bb[(wc * 32 + nr * 16 + l15) * 32 +        \
                                  ((l4 ^ csw) * 8)];                      \
    __builtin_amdgcn_s_setprio(1);                                        \
    _Pragma("unroll")                                                     \
    for (int mr = 0; mr < 4; ++mr)                                        \
      _Pragma("unroll")                                                   \
      for (int nr = 0; nr < 2; ++nr)                                      \
        acc[mr][nr] = __builtin_amdgcn_mfma_f32_16x16x32_f16(             \
            af[mr], bf[nr], acc[mr][nr], 0, 0, 0);                        \
    __builtin_amdgcn_s_setprio(0);                                        \
    __syncthreads();                                                      \
  }

  FSTAGE(0, 0)
  __syncthreads();
  for (int kt = 0; kt < 32; kt += 2) {
    FITER(0, kt)
    FITER(1, kt + 1)
  }

#pragma unroll
  for (int nr = 0; nr < 2; ++nr) {
    const int n = n0 + wc * 32 + nr * 16 + l15;
    const float bv = bias[n];
#pragma unroll
    for (int mr = 0; mr < 4; ++mr)
#pragma unroll
      for (int j = 0; j < 4; ++j) {
        const int m = m0 + wr * 64 + mr * 16 + l4 * 4 + j;
        outF[(size_t)m * N + n] = acc[mr][nr][j] + bv;
      }
  }
}

// ---------------------------------------------------------------------------
// MFMA attention (unchanged from round 10/11: 59.4 us measured).
// ---------------------------------------------------------------------------
#define VPAD 36
__global__ __launch_bounds__(256, 4) void attn_mfma(
    const f16* __restrict__ qkbuf, const f16* __restrict__ vT,
    const unsigned long long* __restrict__ mbits,
    f16* __restrict__ Opart, float* __restrict__ Lpart)
{
  __shared__ f16 Kds[2][32 * 64];     // [key][d], chunk-swizzled, 8 KB
  __shared__ f16 Vds[2][64 * VPAD];   // [d][key+pad], 9 KB

  const int t = threadIdx.x;
  const int w = t >> 6, l = t & 63, l15 = l & 15, l4 = l >> 4;
  const int bh = blockIdx.y, b = bh >> 4, h = bh & 15;
  const int ks = blockIdx.z;
  const int qbase = blockIdx.x * 128 + w * 32;

  f16x8 q00, q01, q10, q11;
  {
    const size_t r0 = (size_t)(b * SS + qbase + l15) * 2048 + h * 64;
    const size_t r1 = (size_t)(b * SS + qbase + 16 + l15) * 2048 + h * 64;
    q00 = *(const f16x8*)(qkbuf + r0 + l4 * 8);
    q01 = *(const f16x8*)(qkbuf + r0 + 32 + l4 * 8);
    q10 = *(const f16x8*)(qkbuf + r1 + l4 * 8);
    q11 = *(const f16x8*)(qkbuf + r1 + 32 + l4 * 8);
  }

  f32x4 accA[4] = {}, accB[4] = {};
  f32x4 accLA = {}, accLB = {};
  f16x8 ones;
#pragma unroll
  for (int i = 0; i < 8; ++i) ones[i] = (f16)1.0f;

  const unsigned int* mA =
      (const unsigned int*)mbits + (size_t)(b * SS + qbase + l15) * 64 + ks * 32;
  const unsigned int* mB =
      (const unsigned int*)mbits + (size_t)(b * SS + qbase + 16 + l15) * 64 + ks * 32;

  const int srow = t >> 3;
  const int scb  = (t & 7) * 8;
  const int sws  = (srow & 7) << 3;
  const f16* kb = qkbuf + (size_t)b * SS * 2048 + 1024 + h * 64 + scb +
                  (size_t)ks * 1024 * 2048;
  const int vd  = t >> 2;
  const int vkb = (t & 3) * 8;
  const f16* vb = vT + ((size_t)bh * 64 + vd) * SS + ks * 1024 + vkb;

  f16x8 kr0; V8 vr0;
#define LOADT(kt)                                                         \
  {                                                                       \
    kr0 = *(const f16x8*)(kb + (size_t)((kt) + srow) * 2048);             \
    vr0.v8 = *(const f16x8*)(vb + (kt));                                  \
  }
#define COMMIT(bi)                                                        \
  {                                                                       \
    *(f16x8*)&Kds[bi][srow * 64 + (scb ^ sws)] = kr0;                     \
    *(f16x4*)&Vds[bi][vd * VPAD + vkb]     = vr0.v4[0];                   \
    *(f16x4*)&Vds[bi][vd * VPAD + vkb + 4] = vr0.v4[1];                   \
  }

  LOADT(0)
  COMMIT(0)
  LOADT(32)
  __syncthreads();

  const int swr = (l15 & 7) << 3;

#define BODY(cur, tI)                                                         \
  {                                                                           \
    const unsigned int mbA = mA[tI];                                          \
    const unsigned int mbB = mB[tI];                                          \
    float pA[8], pB[8];                                                       \
    _Pragma("unroll")                                                         \
    for (int g = 0; g < 2; ++g) {                                             \
      const f16* krow = &Kds[cur][(g * 16 + l15) * 64];                       \
      const f16x8 k0 = *(const f16x8*)(krow + ((l4 * 8) ^ swr));              \
      const f16x8 k1 = *(const f16x8*)(krow + ((32 + l4 * 8) ^ swr));         \
      __builtin_amdgcn_s_setprio(1);                                          \
      f32x4 SA = __builtin_amdgcn_mfma_f32_16x16x32_f16(                      \
          k0, q00, (f32x4){0.f, 0.f, 0.f, 0.f}, 0, 0, 0);                     \
      SA = __builtin_amdgcn_mfma_f32_16x16x32_f16(k1, q01, SA, 0, 0, 0);      \
      f32x4 SB = __builtin_amdgcn_mfma_f32_16x16x32_f16(                      \
          k0, q10, (f32x4){0.f, 0.f, 0.f, 0.f}, 0, 0, 0);                     \
      SB = __builtin_amdgcn_mfma_f32_16x16x32_f16(k1, q11, SB, 0, 0, 0);      \
      __builtin_amdgcn_s_setprio(0);                                          \
      const unsigned int nibA = mbA >> (g * 16 + l4 * 4);                     \
      const unsigned int nibB = mbB >> (g * 16 + l4 * 4);                     \
      _Pragma("unroll")                                                       \
      for (int j = 0; j < 4; ++j) {                                           \
        pA[g * 4 + j] = ((nibA >> j) & 1u) ? 1.0f : EXP2(SA[j]);              \
        pB[g * 4 + j] = ((nibB >> j) & 1u) ? 1.0f : EXP2(SB[j]);              \
      }                                                                       \
    }                                                                         \
    P8 uA, uB;                                                                \
    uA.h2[0] = pk2(pA[0], pA[1]); uA.h2[1] = pk2(pA[2], pA[3]);               \
    uA.h2[2] = pk2(pA[4], pA[5]); uA.h2[3] = pk2(pA[6], pA[7]);               \
    uB.h2[0] = pk2(pB[0], pB[1]); uB.h2[1] = pk2(pB[2], pB[3]);               \
    uB.h2[2] = pk2(pB[4], pB[5]); uB.h2[3] = pk2(pB[6], pB[7]);               \
    __builtin_amdgcn_s_setprio(1);                                            \
    _Pragma("unroll")                                                         \
    for (int dg = 0; dg < 4; ++dg) {                                          \
      const f16* vrow = &Vds[cur][(dg * 16 + l15) * VPAD];                    \
      V8 uv;                                                                  \
      uv.v4[0] = *(const f16x4*)(vrow + l4 * 4);                              \
      uv.v4[1] = *(const f16x4*)(vrow + 16 + l4 * 4);                         \
      accA[dg] = __builtin_amdgcn_mfma_f32_16x16x32_f16(uA.v8, uv.v8,         \
                                                        accA[dg], 0, 0, 0);   \
      accB[dg] = __builtin_amdgcn_mfma_f32_16x16x32_f16(uB.v8, uv.v8,         \
                                                        accB[dg], 0, 0, 0);   \
    }                                                                         \
    accLA = __builtin_amdgcn_mfma_f32_16x16x32_f16(uA.v8, ones, accLA,        \
                                                   0, 0, 0);                  \
    accLB = __builtin_amdgcn_mfma_f32_16x16x32_f16(uB.v8, ones, accLB,        \
                                                   0, 0, 0);                  \
    __builtin_amdgcn_s_setprio(0);                                            \
    if ((tI) + 1 < 32) {                                                      \
      COMMIT((cur) ^ 1)                                                       \
      if ((tI) + 2 < 32) LOADT(((tI) + 2) * 32)                               \
    }                                                                         \
    __syncthreads();                                                          \
  }

  for (int tI = 0; tI < 32; tI += 2) {
    BODY(0, tI)
    BODY(1, tI + 1)
  }

  const size_t obase = (size_t)ks * 4096 * EE;
#pragma unroll
  for (int j = 0; j < 4; ++j) {
    const int qr = l4 * 4 + j;
    const size_t rowA = (size_t)(b * SS + qbase + qr) * EE + h * 64 + l15;
    const size_t rowB = (size_t)(b * SS + qbase + 16 + qr) * EE + h * 64 + l15;
#pragma unroll
    for (int dg = 0; dg < 4; ++dg) {
      Opart[obase + rowA + dg * 16] = (f16)accA[dg][j];
      Opart[obase + rowB + dg * 16] = (f16)accB[dg][j];
    }
    if (l15 == 0) {
      Lpart[(size_t)ks * 4096 * HH + (size_t)(b * SS + qbase + qr) * HH + h] =
          accLA[j];
      Lpart[(size_t)ks * 4096 * HH +
            (size_t)(b * SS + qbase + 16 + qr) * HH + h] = accLB[j];
    }
  }
}

// ---------------------------------------------------------------------------
// combine: aout = (O0 + O1) / (L0 + L1), f16 out. 8 elems/thread.
// ---------------------------------------------------------------------------
__global__ __launch_bounds__(256) void combine(
    const f16* __restrict__ Opart, const float* __restrict__ Lpart,
    f16* __restrict__ aout)
{
  const size_t i = ((size_t)blockIdx.x * 256 + threadIdx.x) * 8;
  const int token = (int)(i >> 10);
  const int h = (int)((i >> 6) & 15);
  const float inv =
      1.0f / (Lpart[(size_t)token * HH + h] +
              Lpart[(size_t)4096 * HH + (size_t)token * HH + h]);
  const f16x8 o0 = *(const f16x8*)(Opart + i);
  const f16x8 o1 = *(const f16x8*)(Opart + (size_t)4096 * EE + i);
  f16x8 o;
#pragma unroll
  for (int j = 0; j < 8; ++j)
    o[j] = (f16)(((float)o0[j] + (float)o1[j]) * inv);
  *(f16x8*)(aout + i) = o;
}

// ---------------------------------------------------------------------------
// Workspace layout (45.6 MB, live-range based; no overlap between live bufs):
//   [ 0.0 ..  2.1)  fckT   (prep .. gemm_fc)
//   [ 2.1 .. 18.9)  qk     (gemm_qkv .. attn)  -- reused as aoutH after attn
//   [18.9 .. 27.3)  vT     (gemm_qkv .. attn)
//   [27.3 .. 28.3)  mbits  (prep .. attn)
//   [28.3 .. 28.8)  Lp     (attn .. combine)
//   [28.8 .. 45.6)  scratch: xh(8.4)+Wt(6.3) (prep .. gemm_qkv), then
//                   Opart 16.8 contiguous    (attn .. combine)
// ---------------------------------------------------------------------------
extern "C" void kernel_launch(void* const* d_in, const int* in_sizes, int n_in,
                              void* d_out, int out_size, void* d_ws,
                              size_t ws_size, hipStream_t stream)
{
  (void)in_sizes; (void)n_in; (void)out_size; (void)ws_size;
  const float* x   = (const float*)d_in[0];
  const int* mask  = (const int*)d_in[1];   // jnp bool staged as int32
  const float* wk  = (const float*)d_in[2];
  const float* wb  = (const float*)d_in[3];
  const float* fck = (const float*)d_in[4];
  const float* fcb = (const float*)d_in[5];
  float* out       = (float*)d_out;

  char* ws = (char*)d_ws;
  f16* fckT = (f16*)(ws);                                   //  2,097,152 B
  f16* qk   = (f16*)(ws + 2097152);                         // 16,777,216 B
  f16* vT   = (f16*)(ws + 18874368);                        //  8,388,608 B
  unsigned long long* mbits = (unsigned long long*)(ws + 27262976); // 1 MB
  float* Lp = (float*)(ws + 28311552);                      //    524,288 B
  char* scratch = ws + 28835840;
  f16* xh    = (f16*)scratch;                               //  8,388,608 B
  f16* Wt    = (f16*)(scratch + 8388608);                   //  6,291,456 B
  f16* Opart = (f16*)scratch;                               // 16,777,216 B
  f16* aoutH = qk;                                          // reuse (qk dead)

  // fused prep: cvt x | wk^T | fck^T | pack mask
  prep<<<11264, 256, 0, stream>>>(x, xh, wk, Wt, fck, fckT, mask, mbits);

  // qkv = x @ w_kernel + w_bias -> qk f16 (Q pre-scaled) + vT f16
  gemm_qkv<<<768, 256, 0, stream>>>(xh, Wt, wb, qk, vT);

  // key-split attention -> partials (Opart overwrites dead xh/Wt scratch)
  attn_mfma<<<dim3(SS / 128, BB * HH, 2), 256, 0, stream>>>(
      qk, vT, mbits, Opart, Lp);
  combine<<<4096 * 1024 / (8 * 256), 256, 0, stream>>>(Opart, Lp, aoutH);

  // out = aout @ fc_kernel + fc_bias (fp32 out)
  gemm_fc<<<512, 256, 0, stream>>>(aoutH, fckT, fcb, out);
}